// Round 3
// baseline (2170.036 us; speedup 1.0000x reference)
//
#include <hip/hip_runtime.h>

#define NN 262144   // rows (embeddings)
#define DD 128      // dim
#define KK 512      // clusters
#define NITER 5

// LDS row stride (bf16 elems): 128 + 8 -> 272B = 17*16B, odd multiple of 16B
// so the 16-lane b128 fragment reads spread across banks (2-way = free).
#define SKH 136

// VALU-fallback LDS strides (floats)
#define SE 132
#define SC 260
#define SS 129

// Ambiguity threshold for the bf16x3 approx argmax. Rigorous error bound:
// 3*2^-16*||e||*||c|| <= 6.6e-4. delta = 2e-3 > 2*eps. (round-2 verified)
#define DELTA 2e-3f

// workspace layout (WS_NEEDED unchanged from round-2 verified gate)
#define WS_A16_BYTES   (NN * 2)                       // u16 assigns
#define WS_SUMS_OFF    (WS_A16_BYTES)                 // 2048 x 128 f32 partials
#define WS_CNTS_OFF    (WS_SUMS_OFF + 2048 * DD * 4)  // 2048 i32 counts
#define WS_NEEDED      (WS_CNTS_OFF + 2048 * 4)
// Overlays INSIDE ws_sums (1 MB), no lifetime overlap per iteration:
//   flags: NN bytes      @ WS_SUMS_OFF          (assign writes -> rescue reads)
//   CH: 512*128 bf16     @ WS_SUMS_OFF + NN     (split_c writes -> assign reads)
//   CL: 512*128 bf16     @ WS_SUMS_OFF + NN + 128K
// update_partial clobbers all three AFTER rescue; combine reads sums only.
// Every byte written before read each call (poison-safe).
#define WS_CH_OFF      (WS_SUMS_OFF + NN)
#define WS_CL_OFF      (WS_CH_OFF + KK * DD * 2)

using s8    = __attribute__((ext_vector_type(8))) short;   // 8 bf16 (4 VGPR)
using f32x4 = __attribute__((ext_vector_type(4))) float;   // MFMA acc

// RNE float -> bf16 bits (finite inputs only)
__device__ __forceinline__ unsigned f2bf(float x) {
    unsigned u = __float_as_uint(x);
    return (u + 0x7fffu + ((u >> 16) & 1u)) >> 16;
}

// split float4 into packed hi/lo bf16 pairs (x = hi + lo + O(2^-16 x))
__device__ __forceinline__ void split4(float4 v, uint2& h, uint2& s) {
    unsigned hx = f2bf(v.x), hy = f2bf(v.y), hz = f2bf(v.z), hw = f2bf(v.w);
    float rx = v.x - __uint_as_float(hx << 16);
    float ry = v.y - __uint_as_float(hy << 16);
    float rz = v.z - __uint_as_float(hz << 16);
    float rw = v.w - __uint_as_float(hw << 16);
    unsigned lx = f2bf(rx), ly = f2bf(ry), lz = f2bf(rz), lw = f2bf(rw);
    h.x = hx | (hy << 16); h.y = hz | (hw << 16);
    s.x = lx | (ly << 16); s.y = lz | (lw << 16);
}

// ---------------------------------------------------------------------------
// Pre-split C (512 x 128 fp32) into bf16 hi/lo, once per iteration.
// ---------------------------------------------------------------------------
__global__ __launch_bounds__(256) void split_c_kernel(
    const float* __restrict__ C, unsigned short* __restrict__ CH,
    unsigned short* __restrict__ CL)
{
    int idx = blockIdx.x * 256 + threadIdx.x;      // 16384 float4s
    float4 v = *(const float4*)&C[(size_t)idx * 4];
    uint2 h, s;
    split4(v, h, s);
    *(uint2*)&CH[(size_t)idx * 4] = h;
    *(uint2*)&CL[(size_t)idx * 4] = s;
}

// ---------------------------------------------------------------------------
// Kernel A: assignment via bf16x3 MFMA GEMM + fused top-2 argmax + flags.
// E tile (128 rows, hi/lo) in LDS (69.6 KB -> 2 blocks/CU, 2 waves/SIMD);
// B fragments stream straight from L2-resident CH/CL (no LDS, no barriers
// in the K/chunk loop). Wave tile 64x64 = 4x4 x mfma_f32_16x16x32_bf16,
// 3 passes (hh, hl, lh). Numerics identical to round-2 verified kernel.
// ---------------------------------------------------------------------------
__global__ __launch_bounds__(256, 2) void assign_kernel(
    const float* __restrict__ E,
    const unsigned short* __restrict__ CH, const unsigned short* __restrict__ CL,
    int* __restrict__ assignv, unsigned short* __restrict__ assign16,
    unsigned char* __restrict__ flags)
{
    __shared__ unsigned short lds[2 * 128 * SKH];   // 69632 B
    unsigned short* EH = lds;
    unsigned short* EL = lds + 128 * SKH;

    const int tid = threadIdx.x;
    const int l   = tid & 63;
    const int wid = tid >> 6;
    const int wr  = wid >> 1;          // wave row-half (rows wr*64..+63)
    const int wc  = wid & 1;           // wave col-half (cols wc*64..+63 of chunk)
    const int c   = l & 15;            // fragment line (A row / B col / D col)
    const int g   = l >> 4;            // k-octet selector; D row group
    const int r0  = blockIdx.x * 128;

    // ---- stage E: 128 rows x 128 k, split hi/lo (once per block)
#pragma unroll
    for (int it = 0; it < 16; ++it) {
        int idx = it * 256 + tid;
        int row = idx >> 5;
        int k4  = (idx & 31) << 2;
        float4 v = *(const float4*)&E[(size_t)(r0 + row) * DD + k4];
        uint2 h, s;
        split4(v, h, s);
        *(uint2*)&EH[row * SKH + k4] = h;
        *(uint2*)&EL[row * SKH + k4] = s;
    }
    __syncthreads();

    float bv[16], sv[16];
    int   bk[16];
#pragma unroll
    for (int i = 0; i < 16; ++i) { bv[i] = -3.4e38f; sv[i] = -3.4e38f; bk[i] = 0; }

    const int aoff0 = (wr * 64 + c) * SKH + g * 8;

    for (int cc = 0; cc < 4; ++cc) {
        const int colbase = cc * 128 + wc * 64 + c;   // this lane's B column

        f32x4 acc[4][4];
#pragma unroll
        for (int rf = 0; rf < 4; ++rf)
#pragma unroll
            for (int cf = 0; cf < 4; ++cf)
                acc[rf][cf] = (f32x4){0.f, 0.f, 0.f, 0.f};

#pragma unroll
        for (int kc = 0; kc < 4; ++kc) {
            const int ko = kc * 32 + g * 8;
            s8 ah[4], al[4], bh[4], bl[4];
#pragma unroll
            for (int rf = 0; rf < 4; ++rf) {
                int off = aoff0 + rf * 16 * SKH + kc * 32;
                ah[rf] = *(const s8*)&EH[off];
                al[rf] = *(const s8*)&EL[off];
            }
#pragma unroll
            for (int cf = 0; cf < 4; ++cf) {
                size_t boff = (size_t)(colbase + cf * 16) * DD + ko;
                bh[cf] = *(const s8*)&CH[boff];
                bl[cf] = *(const s8*)&CL[boff];
            }
#pragma unroll
            for (int rf = 0; rf < 4; ++rf)
#pragma unroll
                for (int cf = 0; cf < 4; ++cf) {
                    acc[rf][cf] = __builtin_amdgcn_mfma_f32_16x16x32_bf16(
                        ah[rf], bh[cf], acc[rf][cf], 0, 0, 0);
                    acc[rf][cf] = __builtin_amdgcn_mfma_f32_16x16x32_bf16(
                        ah[rf], bl[cf], acc[rf][cf], 0, 0, 0);
                    acc[rf][cf] = __builtin_amdgcn_mfma_f32_16x16x32_bf16(
                        al[rf], bh[cf], acc[rf][cf], 0, 0, 0);
                }
        }

        // fold chunk into per-lane running top-2 (ascending k order).
        const int kbase = cc * 128 + wc * 64 + c;
#pragma unroll
        for (int rf = 0; rf < 4; ++rf)
#pragma unroll
            for (int i = 0; i < 4; ++i) {
                const int sidx = rf * 4 + i;
#pragma unroll
                for (int cf = 0; cf < 4; ++cf) {
                    float v = acc[rf][cf][i];
                    int  kg = kbase + cf * 16;
                    if (v > bv[sidx]) { sv[sidx] = bv[sidx]; bv[sidx] = v; bk[sidx] = kg; }
                    else              { sv[sidx] = fmaxf(sv[sidx], v); }
                }
            }
    }

    // cross-lane top-2 butterfly over the 16 column-lanes of each row group
#pragma unroll
    for (int s = 0; s < 16; ++s) {
        float v1 = bv[s], v2 = sv[s]; int k1 = bk[s];
#pragma unroll
        for (int m = 1; m <= 8; m <<= 1) {
            float ov = __shfl_xor(v1, m, 64);
            float os = __shfl_xor(v2, m, 64);
            int   ok = __shfl_xor(k1, m, 64);
            if (ov > v1) { v2 = fmaxf(v1, os); v1 = ov; k1 = ok; }
            else         { v2 = fmaxf(v2, ov); }
        }
        bv[s] = v1; sv[s] = v2; bk[s] = k1;
    }

    // cross-wave (wc halves) top-2 merge via small LDS overlay
    __syncthreads();                   // all EH/EL reads done
    float* mv = (float*)lds;           // [2][128] v1
    int*   mk = (int*)lds + 256;       // [2][128] k1
    float* ms = (float*)lds + 512;     // [2][128] v2
    if (c == 0) {
#pragma unroll
        for (int rf = 0; rf < 4; ++rf)
#pragma unroll
            for (int i = 0; i < 4; ++i) {
                int row = wr * 64 + rf * 16 + g * 4 + i;
                mv[wc * 128 + row] = bv[rf * 4 + i];
                mk[wc * 128 + row] = bk[rf * 4 + i];
                ms[wc * 128 + row] = sv[rf * 4 + i];
            }
    }
    __syncthreads();
    if (tid < 128) {
        float v1 = mv[tid], v2 = ms[tid]; int k1 = mk[tid];
        float ov = mv[128 + tid], os = ms[128 + tid]; int ok = mk[128 + tid];
        if (ov > v1) { v2 = fmaxf(v1, os); v1 = ov; k1 = ok; }
        else         { v2 = fmaxf(v2, ov); }
        assignv[r0 + tid] = k1;
        assign16[r0 + tid] = (unsigned short)k1;
        flags[r0 + tid] = (v1 - v2 < DELTA) ? 1 : 0;
    }
}

// ---------------------------------------------------------------------------
// Rescue: exact fp32 re-argmax (first-occurrence) for flagged rows only.
// ---------------------------------------------------------------------------
__global__ __launch_bounds__(256) void rescue_kernel(
    const float* __restrict__ E, const float* __restrict__ C,
    const unsigned char* __restrict__ flags,
    int* __restrict__ assignv, unsigned short* __restrict__ assign16)
{
    __shared__ int   rows[128];
    __shared__ int   nf;
    __shared__ float ev[DD];
    __shared__ float rv[4];
    __shared__ int   rk[4];

    const int tid  = threadIdx.x;
    const int base = blockIdx.x * 128;

    if (tid == 0) nf = 0;
    __syncthreads();
    if (tid < 128 && flags[base + tid]) {
        int p = atomicAdd(&nf, 1);
        rows[p] = base + tid;
    }
    __syncthreads();
    const int n = nf;
    if (n == 0) return;

    for (int i = 0; i < n; ++i) {
        const int row = rows[i];
        if (tid < 32)
            *(float4*)&ev[tid * 4] = *(const float4*)&E[(size_t)row * DD + tid * 4];
        __syncthreads();

        // two exact fp32 dots per thread: k = tid, k = tid + 256
        float d0 = 0.f, d1 = 0.f;
        for (int q = 0; q < 32; ++q) {
            float4 e4 = *(const float4*)&ev[q * 4];
            float4 c0 = *(const float4*)&C[(size_t)tid * DD + q * 4];
            float4 c1 = *(const float4*)&C[(size_t)(tid + 256) * DD + q * 4];
            d0 = fmaf(e4.x, c0.x, d0); d0 = fmaf(e4.y, c0.y, d0);
            d0 = fmaf(e4.z, c0.z, d0); d0 = fmaf(e4.w, c0.w, d0);
            d1 = fmaf(e4.x, c1.x, d1); d1 = fmaf(e4.y, c1.y, d1);
            d1 = fmaf(e4.z, c1.z, d1); d1 = fmaf(e4.w, c1.w, d1);
        }
        float v = (d0 >= d1) ? d0 : d1;          // >= keeps lower k on tie
        int   k = (d0 >= d1) ? tid : tid + 256;
#pragma unroll
        for (int m = 1; m <= 32; m <<= 1) {
            float ov = __shfl_xor(v, m, 64);
            int   ok = __shfl_xor(k, m, 64);
            if (ov > v || (ov == v && ok < k)) { v = ov; k = ok; }
        }
        if ((tid & 63) == 0) { rv[tid >> 6] = v; rk[tid >> 6] = k; }
        __syncthreads();
        if (tid == 0) {
            float bv2 = rv[0]; int bk2 = rk[0];
#pragma unroll
            for (int w = 1; w < 4; ++w)
                if (rv[w] > bv2 || (rv[w] == bv2 && rk[w] < bk2)) { bv2 = rv[w]; bk2 = rk[w]; }
            assignv[row] = bk2;
            assign16[row] = (unsigned short)bk2;
        }
        __syncthreads();   // ev/rv/rk reuse next row
    }
}

// ---------------------------------------------------------------------------
// Fallback assignment (pure fp32 VALU, verified) for tiny ws.
// ---------------------------------------------------------------------------
__global__ __launch_bounds__(256, 2) void assign_valu_kernel(
    const float* __restrict__ E, const float* __restrict__ C,
    int* __restrict__ assignv, unsigned short* __restrict__ assign16)
{
    __shared__ float smem[32 * SE + 32 * SC];
    float* ET = smem;
    float* CT = smem + 32 * SE;
    float* sval = smem;
    int*   sidx = ((int*)smem) + 32 * SS;

    const int tid = threadIdx.x;
    const int tx  = tid & 31;
    const int ty  = tid >> 5;
    const int r0  = blockIdx.x * 128;

    float bbv = 0.f;
    int   bbk = 0;

    for (int chunk = 0; chunk < 2; ++chunk) {
        const int k0 = chunk * 256;
        float acc[16][8];
#pragma unroll
        for (int i = 0; i < 16; ++i)
#pragma unroll
            for (int j = 0; j < 8; ++j) acc[i][j] = 0.f;

        for (int sub = 0; sub < 4; ++sub) {
            const int d0 = sub * 32;
            __syncthreads();
#pragma unroll
            for (int it = 0; it < 4; ++it) {
                int idx = tid + it * 256;
                int r = idx >> 3, q = idx & 7;
                float4 v = *(const float4*)&E[(r0 + r) * DD + d0 + q * 4];
                ET[(q * 4 + 0) * SE + r] = v.x;
                ET[(q * 4 + 1) * SE + r] = v.y;
                ET[(q * 4 + 2) * SE + r] = v.z;
                ET[(q * 4 + 3) * SE + r] = v.w;
            }
#pragma unroll
            for (int it = 0; it < 8; ++it) {
                int idx = tid + it * 256;
                int k = idx >> 3, q = idx & 7;
                float4 v = *(const float4*)&C[(k0 + k) * DD + d0 + q * 4];
                CT[(q * 4 + 0) * SC + k] = v.x;
                CT[(q * 4 + 1) * SC + k] = v.y;
                CT[(q * 4 + 2) * SC + k] = v.z;
                CT[(q * 4 + 3) * SC + k] = v.w;
            }
            __syncthreads();
#pragma unroll 4
            for (int d = 0; d < 32; ++d) {
                float4 a0 = *(const float4*)&ET[d * SE + ty * 16];
                float4 a1 = *(const float4*)&ET[d * SE + ty * 16 + 4];
                float4 a2 = *(const float4*)&ET[d * SE + ty * 16 + 8];
                float4 a3 = *(const float4*)&ET[d * SE + ty * 16 + 12];
                float4 b0 = *(const float4*)&CT[d * SC + tx * 4];
                float4 b1 = *(const float4*)&CT[d * SC + 128 + tx * 4];
                float ra[16] = {a0.x, a0.y, a0.z, a0.w, a1.x, a1.y, a1.z, a1.w,
                                a2.x, a2.y, a2.z, a2.w, a3.x, a3.y, a3.z, a3.w};
                float rb[8]  = {b0.x, b0.y, b0.z, b0.w, b1.x, b1.y, b1.z, b1.w};
#pragma unroll
                for (int i = 0; i < 16; ++i)
#pragma unroll
                    for (int j = 0; j < 8; ++j)
                        acc[i][j] = fmaf(ra[i], rb[j], acc[i][j]);
            }
        }
        __syncthreads();

#pragma unroll
        for (int i = 0; i < 16; ++i) {
            float bv = acc[i][0]; int bj = 0;
#pragma unroll
            for (int j = 1; j < 8; ++j)
                if (acc[i][j] > bv) { bv = acc[i][j]; bj = j; }
            int row = ty * 16 + i;
            int gk = k0 + ((bj < 4) ? (tx * 4 + bj) : (128 + tx * 4 + (bj - 4)));
            sval[tx * SS + row] = bv;
            sidx[tx * SS + row] = gk;
        }
        __syncthreads();
        if (tid < 128) {
            float bv = sval[tid]; int bi = sidx[tid];
            for (int t = 1; t < 32; ++t) {
                float v = sval[t * SS + tid];
                int   x = sidx[t * SS + tid];
                if (v > bv || (v == bv && x < bi)) { bv = v; bi = x; }
            }
            if (chunk == 0 || bv > bbv || (bv == bbv && bi < bbk)) {
                bbv = bv; bbk = bi;
            }
        }
    }
    if (tid < 128) {
        assignv[r0 + tid] = bbk;
        if (assign16) assign16[r0 + tid] = (unsigned short)bbk;
    }
}

// ---------------------------------------------------------------------------
// Fast M-step, phase 1: 2048 blocks = 4 per cluster. Deterministic.
// ---------------------------------------------------------------------------
__global__ __launch_bounds__(256) void update_partial_kernel(
    const float* __restrict__ E, const unsigned short* __restrict__ assign16,
    float* __restrict__ ws_sums, int* __restrict__ ws_cnts)
{
    const int b   = blockIdx.x;
    const int k   = b >> 2;
    const int qtr = b & 3;

    __shared__ float acc[4][DD];
    __shared__ int   cnts[4];

    const int tid  = threadIdx.x;
    const int w    = tid >> 6;
    const int lane = tid & 63;

    float a0 = 0.f, a1 = 0.f;
    int cnt = 0;
    const int wbase = qtr * (NN / 4) + w * (NN / 16);

    for (int it = 0; it < (NN / 16) / 512; ++it) {
        const int off = wbase + it * 512;
        uint4 p = *(const uint4*)&assign16[off + lane * 8];
        unsigned v[4] = {p.x, p.y, p.z, p.w};
#pragma unroll
        for (int h = 0; h < 4; ++h) {
            int lo = (int)(v[h] & 0xffffu);
            int hi = (int)(v[h] >> 16);
            unsigned long long mlo = __ballot(lo == k);
            unsigned long long mhi = __ballot(hi == k);
            cnt += (int)__popcll(mlo) + (int)__popcll(mhi);
            while (mlo) {
                int b2 = __ffsll((long long)mlo) - 1; mlo &= mlo - 1;
                int row = off + b2 * 8 + h * 2;
                float2 e = *(const float2*)&E[(size_t)row * DD + lane * 2];
                a0 += e.x; a1 += e.y;
            }
            while (mhi) {
                int b2 = __ffsll((long long)mhi) - 1; mhi &= mhi - 1;
                int row = off + b2 * 8 + h * 2 + 1;
                float2 e = *(const float2*)&E[(size_t)row * DD + lane * 2];
                a0 += e.x; a1 += e.y;
            }
        }
    }
    acc[w][lane * 2]     = a0;
    acc[w][lane * 2 + 1] = a1;
    if (lane == 0) cnts[w] = cnt;
    __syncthreads();
    if (tid < DD)
        ws_sums[(size_t)b * DD + tid] = acc[0][tid] + acc[1][tid] + acc[2][tid] + acc[3][tid];
    if (tid == 0)
        ws_cnts[b] = cnts[0] + cnts[1] + cnts[2] + cnts[3];
}

// ---------------------------------------------------------------------------
// Fast M-step, phase 2: combine 4 partials, mean, L2-normalize.
// ---------------------------------------------------------------------------
__global__ __launch_bounds__(128) void update_combine_kernel(
    const float* __restrict__ ws_sums, const int* __restrict__ ws_cnts,
    float* __restrict__ C)
{
    const int k = blockIdx.x, t = threadIdx.x;
    __shared__ float red[2];
    const int w = t >> 6, lane = t & 63;

    float s = ws_sums[(size_t)(4 * k + 0) * DD + t]
            + ws_sums[(size_t)(4 * k + 1) * DD + t]
            + ws_sums[(size_t)(4 * k + 2) * DD + t]
            + ws_sums[(size_t)(4 * k + 3) * DD + t];
    int cnt = ws_cnts[4 * k] + ws_cnts[4 * k + 1] + ws_cnts[4 * k + 2] + ws_cnts[4 * k + 3];
    float m = (cnt > 0) ? s / (float)cnt : C[k * DD + t];

    float sq = m * m;
#pragma unroll
    for (int o = 32; o > 0; o >>= 1) sq += __shfl_down(sq, o, 64);
    if (lane == 0) red[w] = sq;
    __syncthreads();
    float nrm = fmaxf(sqrtf(red[0] + red[1]), 1e-12f);
    C[k * DD + t] = m / nrm;
}

// ---------------------------------------------------------------------------
// Fallback M-step (no d_ws usage).
// ---------------------------------------------------------------------------
__global__ __launch_bounds__(256) void update_kernel(
    const float* __restrict__ E, const int* __restrict__ assignv,
    float* __restrict__ C)
{
    const int k = blockIdx.x;
    __shared__ float acc[4][DD];
    __shared__ int   cnts[4];
    __shared__ float red[4];

    const int tid  = threadIdx.x;
    const int w    = tid >> 6;
    const int lane = tid & 63;

    float a0 = 0.f, a1 = 0.f;
    int cnt = 0;
    const int per_wave = NN / 4;
    const int base = w * per_wave;

    for (int it = 0; it < per_wave / 256; ++it) {
        const int off = base + it * 256;
        int4 as = *(const int4*)&assignv[off + lane * 4];
        int av[4] = {as.x, as.y, as.z, as.w};
#pragma unroll
        for (int ci = 0; ci < 4; ++ci) {
            unsigned long long m = __ballot(av[ci] == k);
            cnt += (int)__popcll(m);
            while (m) {
                int b = __ffsll((long long)m) - 1;
                m &= m - 1;
                int r = off + b * 4 + ci;
                float2 v = *(const float2*)&E[r * DD + lane * 2];
                a0 += v.x; a1 += v.y;
            }
        }
    }
    acc[w][lane * 2]     = a0;
    acc[w][lane * 2 + 1] = a1;
    if (lane == 0) cnts[w] = cnt;
    __syncthreads();

    float m = 0.f;
    const int ctot = cnts[0] + cnts[1] + cnts[2] + cnts[3];
    if (tid < DD) {
        float s = acc[0][tid] + acc[1][tid] + acc[2][tid] + acc[3][tid];
        m = (ctot > 0) ? s / (float)ctot : C[k * DD + tid];
    }
    float sq = m * m;
#pragma unroll
    for (int o = 32; o > 0; o >>= 1) sq += __shfl_down(sq, o, 64);
    if (lane == 0) red[w] = sq;
    __syncthreads();
    if (tid < DD) {
        float nrm = fmaxf(sqrtf(red[0] + red[1]), 1e-12f);
        C[k * DD + tid] = m / nrm;
    }
}

__global__ void finalize_kernel(float* __restrict__ out)
{
    int i = blockIdx.x * 256 + threadIdx.x;
    if (i < NN) {
        int a = ((const int*)out)[i];
        out[i] = (float)a;
    }
}

extern "C" void kernel_launch(void* const* d_in, const int* in_sizes, int n_in,
                              void* d_out, int out_size, void* d_ws, size_t ws_size,
                              hipStream_t stream)
{
    (void)in_sizes; (void)n_in; (void)out_size;

    const float* E  = (const float*)d_in[0];
    const float* C0 = (const float*)d_in[1];
    // num_iters (d_in[2]) is a fixed scalar = 5; hardcoded (graph-safe).

    float* out     = (float*)d_out;
    float* C       = out + NN;        // centroids in d_out tail
    int*   assignv = (int*)out;       // assign ints in d_out head

    const bool fast = (ws_size >= (size_t)WS_NEEDED);
    unsigned short* assign16 = fast ? (unsigned short*)d_ws : nullptr;
    float* ws_sums = fast ? (float*)((char*)d_ws + WS_SUMS_OFF) : nullptr;
    int*   ws_cnts = fast ? (int*)((char*)d_ws + WS_CNTS_OFF) : nullptr;
    unsigned char* flags = fast ? (unsigned char*)d_ws + WS_SUMS_OFF : nullptr;
    unsigned short* CH = fast ? (unsigned short*)((char*)d_ws + WS_CH_OFF) : nullptr;
    unsigned short* CL = fast ? (unsigned short*)((char*)d_ws + WS_CL_OFF) : nullptr;

    hipMemcpyAsync(C, C0, (size_t)KK * DD * sizeof(float),
                   hipMemcpyDeviceToDevice, stream);

    for (int it = 0; it < NITER; ++it) {
        if (fast) {
            split_c_kernel<<<KK * DD / 4 / 256, 256, 0, stream>>>(C, CH, CL);
            assign_kernel<<<NN / 128, 256, 0, stream>>>(E, CH, CL, assignv, assign16, flags);
            rescue_kernel<<<NN / 128, 256, 0, stream>>>(E, C, flags, assignv, assign16);
            update_partial_kernel<<<2048, 256, 0, stream>>>(E, assign16, ws_sums, ws_cnts);
            update_combine_kernel<<<KK, 128, 0, stream>>>(ws_sums, ws_cnts, C);
        } else {
            assign_valu_kernel<<<NN / 128, 256, 0, stream>>>(E, C, assignv, nullptr);
            update_kernel<<<KK, 256, 0, stream>>>(E, assignv, C);
        }
    }
    finalize_kernel<<<(NN + 255) / 256, 256, 0, stream>>>(out);
}

// Round 4
// 1475.449 us; speedup vs baseline: 1.4708x; 1.4708x over previous
//
#include <hip/hip_runtime.h>

#define NN 262144   // rows (embeddings)
#define DD 128      // dim
#define KK 512      // clusters
#define NITER 5

// LDS row stride (bf16 elems): 128 + 8 -> 272B = 17*16B, odd multiple of 16B
// so the 16-lane b128 fragment reads spread across banks (2-way = free).
#define SKH 136

// VALU-fallback LDS strides (floats)
#define SE 132
#define SC 260
#define SS 129

// Ambiguity threshold for the bf16x3 approx argmax. Rigorous error bound:
// 3*2^-16*||e||*||c|| <= 6.6e-4. delta = 2e-3 > 2*eps. (round-2 verified)
#define DELTA 2e-3f

// workspace layout (WS_NEEDED unchanged from round-2 verified gate)
#define WS_A16_BYTES   (NN * 2)                       // u16 assigns
#define WS_SUMS_OFF    (WS_A16_BYTES)                 // 2048 x 128 f32 partials
#define WS_CNTS_OFF    (WS_SUMS_OFF + 2048 * DD * 4)  // 2048 i32 counts
#define WS_NEEDED      (WS_CNTS_OFF + 2048 * 4)
// Overlays INSIDE ws_sums (1 MB), no lifetime overlap per iteration:
//   flags: NN bytes      @ WS_SUMS_OFF          (assign writes -> rescue reads)
//   CH: 512*128 bf16     @ WS_SUMS_OFF + NN     (split_c writes -> assign reads)
//   CL: 512*128 bf16     @ WS_SUMS_OFF + NN + 128K
// update_partial clobbers all three AFTER rescue; combine reads sums only.
// Every byte written before read each call (poison-safe).
#define WS_CH_OFF      (WS_SUMS_OFF + NN)
#define WS_CL_OFF      (WS_CH_OFF + KK * DD * 2)

using s8    = __attribute__((ext_vector_type(8))) short;   // 8 bf16 (4 VGPR)
using f32x4 = __attribute__((ext_vector_type(4))) float;   // MFMA acc

// RNE float -> bf16 bits (finite inputs only)
__device__ __forceinline__ unsigned f2bf(float x) {
    unsigned u = __float_as_uint(x);
    return (u + 0x7fffu + ((u >> 16) & 1u)) >> 16;
}

// split float4 into packed hi/lo bf16 pairs (x = hi + lo + O(2^-16 x))
__device__ __forceinline__ void split4(float4 v, uint2& h, uint2& s) {
    unsigned hx = f2bf(v.x), hy = f2bf(v.y), hz = f2bf(v.z), hw = f2bf(v.w);
    float rx = v.x - __uint_as_float(hx << 16);
    float ry = v.y - __uint_as_float(hy << 16);
    float rz = v.z - __uint_as_float(hz << 16);
    float rw = v.w - __uint_as_float(hw << 16);
    unsigned lx = f2bf(rx), ly = f2bf(ry), lz = f2bf(rz), lw = f2bf(rw);
    h.x = hx | (hy << 16); h.y = hz | (hw << 16);
    s.x = lx | (ly << 16); s.y = lz | (lw << 16);
}

// ---------------------------------------------------------------------------
// Pre-split C into bf16 hi/lo in FRAGMENT-MAJOR layout, once per iteration.
// Layout: elem index = group*512 + (g*16 + c)*8 + e, where for column col and
// k: group = (col>>4)*4 + (k>>5), g = (k>>3)&3, c = col&15, e = k&7.
// A wave's B-fragment read (lanes l = g*16+c) for a given (col-group, kc) is
// then one contiguous 64x16B = 1KB segment.
// ---------------------------------------------------------------------------
__global__ __launch_bounds__(256) void split_c_kernel(
    const float* __restrict__ C, unsigned short* __restrict__ CH,
    unsigned short* __restrict__ CL)
{
    int idx = blockIdx.x * 256 + threadIdx.x;      // 16384 float4s
    int col = idx >> 5;            // 0..511
    int k4  = (idx & 31) << 2;     // 0,4,..,124
    float4 v = *(const float4*)&C[(size_t)col * DD + k4];
    uint2 h, s;
    split4(v, h, s);
    int group = (col >> 4) * 4 + (k4 >> 5);
    int inner = ((k4 >> 3) & 3) * 16 + (col & 15);
    int off   = group * 512 + inner * 8 + (k4 & 7);   // multiple of 4 elems
    *(uint2*)&CH[off] = h;
    *(uint2*)&CL[off] = s;
}

// ---------------------------------------------------------------------------
// Kernel A: assignment via bf16x3 MFMA GEMM + fused top-2 argmax + flags.
// E tile (128 rows, hi/lo) in LDS (69.6 KB -> 2 blocks/CU). B fragments
// stream from fragment-major CH/CL as contiguous 1KB wave-loads, software-
// pipelined one k-step ahead (double-buffered regs, static indices).
// Flattened 16-step (cc,kc) loop, fully unrolled. Numerics identical to
// the round-2/3 verified kernel (same products, same fold order).
// ---------------------------------------------------------------------------
__global__ __launch_bounds__(256, 2) void assign_kernel(
    const float* __restrict__ E,
    const unsigned short* __restrict__ CH, const unsigned short* __restrict__ CL,
    int* __restrict__ assignv, unsigned short* __restrict__ assign16,
    unsigned char* __restrict__ flags)
{
    __shared__ unsigned short lds[2 * 128 * SKH];   // 69632 B
    unsigned short* EH = lds;
    unsigned short* EL = lds + 128 * SKH;

    const int tid = threadIdx.x;
    const int l   = tid & 63;
    const int wid = tid >> 6;
    const int wr  = wid >> 1;          // wave row-half (rows wr*64..+63)
    const int wc  = wid & 1;           // wave col-half (cols wc*64..+63 of chunk)
    const int c   = l & 15;            // fragment line (A row / B col / D col)
    const int g   = l >> 4;            // k-octet selector; D row group
    const int r0  = blockIdx.x * 128;

    // ---- stage E: 128 rows x 128 k, split hi/lo (once per block)
#pragma unroll
    for (int it = 0; it < 16; ++it) {
        int idx = it * 256 + tid;
        int row = idx >> 5;
        int k4  = (idx & 31) << 2;
        float4 v = *(const float4*)&E[(size_t)(r0 + row) * DD + k4];
        uint2 h, s;
        split4(v, h, s);
        *(uint2*)&EH[row * SKH + k4] = h;
        *(uint2*)&EL[row * SKH + k4] = s;
    }
    __syncthreads();

    float bv[16], sv[16];
    int   bk[16];
#pragma unroll
    for (int i = 0; i < 16; ++i) { bv[i] = -3.4e38f; sv[i] = -3.4e38f; bk[i] = 0; }

    const int aoff0 = (wr * 64 + c) * SKH + g * 8;
    const int bbase = wc * 16 * 512 + l * 8;       // per-thread B base (elems)

    s8 bh[2][4], bl[2][4];                         // double buffer over t
    // preload t=0 (cc=0, kc=0)
#pragma unroll
    for (int cf = 0; cf < 4; ++cf) {
        int off = bbase + (cf * 4) * 512;
        bh[0][cf] = *(const s8*)&CH[off];
        bl[0][cf] = *(const s8*)&CL[off];
    }

    f32x4 acc[4][4];

#pragma unroll
    for (int t = 0; t < 16; ++t) {
        const int cc  = t >> 2, kc = t & 3;
        const int cur = t & 1,  nxt = cur ^ 1;

        if (kc == 0) {
#pragma unroll
            for (int rf = 0; rf < 4; ++rf)
#pragma unroll
                for (int cf = 0; cf < 4; ++cf)
                    acc[rf][cf] = (f32x4){0.f, 0.f, 0.f, 0.f};
        }

        // prefetch next k-step's B fragments (static buffer index after unroll)
        if (t < 15) {
            const int t1 = t + 1, cc1 = t1 >> 2, kc1 = t1 & 3;
#pragma unroll
            for (int cf = 0; cf < 4; ++cf) {
                int off = bbase + (cc1 * 32 + cf * 4 + kc1) * 512;
                bh[nxt][cf] = *(const s8*)&CH[off];
                bl[nxt][cf] = *(const s8*)&CL[off];
            }
        }

        s8 ah[4], al[4];
#pragma unroll
        for (int rf = 0; rf < 4; ++rf) {
            int off = aoff0 + rf * 16 * SKH + kc * 32;
            ah[rf] = *(const s8*)&EH[off];
            al[rf] = *(const s8*)&EL[off];
        }

#pragma unroll
        for (int rf = 0; rf < 4; ++rf)
#pragma unroll
            for (int cf = 0; cf < 4; ++cf) {
                acc[rf][cf] = __builtin_amdgcn_mfma_f32_16x16x32_bf16(
                    ah[rf], bh[cur][cf], acc[rf][cf], 0, 0, 0);
                acc[rf][cf] = __builtin_amdgcn_mfma_f32_16x16x32_bf16(
                    ah[rf], bl[cur][cf], acc[rf][cf], 0, 0, 0);
                acc[rf][cf] = __builtin_amdgcn_mfma_f32_16x16x32_bf16(
                    al[rf], bh[cur][cf], acc[rf][cf], 0, 0, 0);
            }

        // fold chunk into per-lane running top-2 (ascending k order).
        if (kc == 3) {
            const int kbase = cc * 128 + wc * 64 + c;
#pragma unroll
            for (int rf = 0; rf < 4; ++rf)
#pragma unroll
                for (int i = 0; i < 4; ++i) {
                    const int sidx = rf * 4 + i;
#pragma unroll
                    for (int cf = 0; cf < 4; ++cf) {
                        float v = acc[rf][cf][i];
                        int  kg = kbase + cf * 16;
                        if (v > bv[sidx]) { sv[sidx] = bv[sidx]; bv[sidx] = v; bk[sidx] = kg; }
                        else              { sv[sidx] = fmaxf(sv[sidx], v); }
                    }
                }
        }
    }

    // cross-lane top-2 butterfly over the 16 column-lanes of each row group
#pragma unroll
    for (int s = 0; s < 16; ++s) {
        float v1 = bv[s], v2 = sv[s]; int k1 = bk[s];
#pragma unroll
        for (int m = 1; m <= 8; m <<= 1) {
            float ov = __shfl_xor(v1, m, 64);
            float os = __shfl_xor(v2, m, 64);
            int   ok = __shfl_xor(k1, m, 64);
            if (ov > v1) { v2 = fmaxf(v1, os); v1 = ov; k1 = ok; }
            else         { v2 = fmaxf(v2, ov); }
        }
        bv[s] = v1; sv[s] = v2; bk[s] = k1;
    }

    // cross-wave (wc halves) top-2 merge via small LDS overlay
    __syncthreads();                   // all EH/EL reads done
    float* mv = (float*)lds;           // [2][128] v1
    int*   mk = (int*)lds + 256;       // [2][128] k1
    float* ms = (float*)lds + 512;     // [2][128] v2
    if (c == 0) {
#pragma unroll
        for (int rf = 0; rf < 4; ++rf)
#pragma unroll
            for (int i = 0; i < 4; ++i) {
                int row = wr * 64 + rf * 16 + g * 4 + i;
                mv[wc * 128 + row] = bv[rf * 4 + i];
                mk[wc * 128 + row] = bk[rf * 4 + i];
                ms[wc * 128 + row] = sv[rf * 4 + i];
            }
    }
    __syncthreads();
    if (tid < 128) {
        float v1 = mv[tid], v2 = ms[tid]; int k1 = mk[tid];
        float ov = mv[128 + tid], os = ms[128 + tid]; int ok = mk[128 + tid];
        if (ov > v1) { v2 = fmaxf(v1, os); v1 = ov; k1 = ok; }
        else         { v2 = fmaxf(v2, ov); }
        assignv[r0 + tid] = k1;
        assign16[r0 + tid] = (unsigned short)k1;
        flags[r0 + tid] = (v1 - v2 < DELTA) ? 1 : 0;
    }
}

// ---------------------------------------------------------------------------
// Rescue: exact fp32 re-argmax (first-occurrence) for flagged rows only.
// ---------------------------------------------------------------------------
__global__ __launch_bounds__(256) void rescue_kernel(
    const float* __restrict__ E, const float* __restrict__ C,
    const unsigned char* __restrict__ flags,
    int* __restrict__ assignv, unsigned short* __restrict__ assign16)
{
    __shared__ int   rows[128];
    __shared__ int   nf;
    __shared__ float ev[DD];
    __shared__ float rv[4];
    __shared__ int   rk[4];

    const int tid  = threadIdx.x;
    const int base = blockIdx.x * 128;

    if (tid == 0) nf = 0;
    __syncthreads();
    if (tid < 128 && flags[base + tid]) {
        int p = atomicAdd(&nf, 1);
        rows[p] = base + tid;
    }
    __syncthreads();
    const int n = nf;
    if (n == 0) return;

    for (int i = 0; i < n; ++i) {
        const int row = rows[i];
        if (tid < 32)
            *(float4*)&ev[tid * 4] = *(const float4*)&E[(size_t)row * DD + tid * 4];
        __syncthreads();

        // two exact fp32 dots per thread: k = tid, k = tid + 256
        float d0 = 0.f, d1 = 0.f;
        for (int q = 0; q < 32; ++q) {
            float4 e4 = *(const float4*)&ev[q * 4];
            float4 c0 = *(const float4*)&C[(size_t)tid * DD + q * 4];
            float4 c1 = *(const float4*)&C[(size_t)(tid + 256) * DD + q * 4];
            d0 = fmaf(e4.x, c0.x, d0); d0 = fmaf(e4.y, c0.y, d0);
            d0 = fmaf(e4.z, c0.z, d0); d0 = fmaf(e4.w, c0.w, d0);
            d1 = fmaf(e4.x, c1.x, d1); d1 = fmaf(e4.y, c1.y, d1);
            d1 = fmaf(e4.z, c1.z, d1); d1 = fmaf(e4.w, c1.w, d1);
        }
        float v = (d0 >= d1) ? d0 : d1;          // >= keeps lower k on tie
        int   k = (d0 >= d1) ? tid : tid + 256;
#pragma unroll
        for (int m = 1; m <= 32; m <<= 1) {
            float ov = __shfl_xor(v, m, 64);
            int   ok = __shfl_xor(k, m, 64);
            if (ov > v || (ov == v && ok < k)) { v = ov; k = ok; }
        }
        if ((tid & 63) == 0) { rv[tid >> 6] = v; rk[tid >> 6] = k; }
        __syncthreads();
        if (tid == 0) {
            float bv2 = rv[0]; int bk2 = rk[0];
#pragma unroll
            for (int w = 1; w < 4; ++w)
                if (rv[w] > bv2 || (rv[w] == bv2 && rk[w] < bk2)) { bv2 = rv[w]; bk2 = rk[w]; }
            assignv[row] = bk2;
            assign16[row] = (unsigned short)bk2;
        }
        __syncthreads();   // ev/rv/rk reuse next row
    }
}

// ---------------------------------------------------------------------------
// Fallback assignment (pure fp32 VALU, verified) for tiny ws.
// ---------------------------------------------------------------------------
__global__ __launch_bounds__(256, 2) void assign_valu_kernel(
    const float* __restrict__ E, const float* __restrict__ C,
    int* __restrict__ assignv, unsigned short* __restrict__ assign16)
{
    __shared__ float smem[32 * SE + 32 * SC];
    float* ET = smem;
    float* CT = smem + 32 * SE;
    float* sval = smem;
    int*   sidx = ((int*)smem) + 32 * SS;

    const int tid = threadIdx.x;
    const int tx  = tid & 31;
    const int ty  = tid >> 5;
    const int r0  = blockIdx.x * 128;

    float bbv = 0.f;
    int   bbk = 0;

    for (int chunk = 0; chunk < 2; ++chunk) {
        const int k0 = chunk * 256;
        float acc[16][8];
#pragma unroll
        for (int i = 0; i < 16; ++i)
#pragma unroll
            for (int j = 0; j < 8; ++j) acc[i][j] = 0.f;

        for (int sub = 0; sub < 4; ++sub) {
            const int d0 = sub * 32;
            __syncthreads();
#pragma unroll
            for (int it = 0; it < 4; ++it) {
                int idx = tid + it * 256;
                int r = idx >> 3, q = idx & 7;
                float4 v = *(const float4*)&E[(r0 + r) * DD + d0 + q * 4];
                ET[(q * 4 + 0) * SE + r] = v.x;
                ET[(q * 4 + 1) * SE + r] = v.y;
                ET[(q * 4 + 2) * SE + r] = v.z;
                ET[(q * 4 + 3) * SE + r] = v.w;
            }
#pragma unroll
            for (int it = 0; it < 8; ++it) {
                int idx = tid + it * 256;
                int k = idx >> 3, q = idx & 7;
                float4 v = *(const float4*)&C[(k0 + k) * DD + d0 + q * 4];
                CT[(q * 4 + 0) * SC + k] = v.x;
                CT[(q * 4 + 1) * SC + k] = v.y;
                CT[(q * 4 + 2) * SC + k] = v.z;
                CT[(q * 4 + 3) * SC + k] = v.w;
            }
            __syncthreads();
#pragma unroll 4
            for (int d = 0; d < 32; ++d) {
                float4 a0 = *(const float4*)&ET[d * SE + ty * 16];
                float4 a1 = *(const float4*)&ET[d * SE + ty * 16 + 4];
                float4 a2 = *(const float4*)&ET[d * SE + ty * 16 + 8];
                float4 a3 = *(const float4*)&ET[d * SE + ty * 16 + 12];
                float4 b0 = *(const float4*)&CT[d * SC + tx * 4];
                float4 b1 = *(const float4*)&CT[d * SC + 128 + tx * 4];
                float ra[16] = {a0.x, a0.y, a0.z, a0.w, a1.x, a1.y, a1.z, a1.w,
                                a2.x, a2.y, a2.z, a2.w, a3.x, a3.y, a3.z, a3.w};
                float rb[8]  = {b0.x, b0.y, b0.z, b0.w, b1.x, b1.y, b1.z, b1.w};
#pragma unroll
                for (int i = 0; i < 16; ++i)
#pragma unroll
                    for (int j = 0; j < 8; ++j)
                        acc[i][j] = fmaf(ra[i], rb[j], acc[i][j]);
            }
        }
        __syncthreads();

#pragma unroll
        for (int i = 0; i < 16; ++i) {
            float bv = acc[i][0]; int bj = 0;
#pragma unroll
            for (int j = 1; j < 8; ++j)
                if (acc[i][j] > bv) { bv = acc[i][j]; bj = j; }
            int row = ty * 16 + i;
            int gk = k0 + ((bj < 4) ? (tx * 4 + bj) : (128 + tx * 4 + (bj - 4)));
            sval[tx * SS + row] = bv;
            sidx[tx * SS + row] = gk;
        }
        __syncthreads();
        if (tid < 128) {
            float bv = sval[tid]; int bi = sidx[tid];
            for (int t = 1; t < 32; ++t) {
                float v = sval[t * SS + tid];
                int   x = sidx[t * SS + tid];
                if (v > bv || (v == bv && x < bi)) { bv = v; bi = x; }
            }
            if (chunk == 0 || bv > bbv || (bv == bbv && bi < bbk)) {
                bbv = bv; bbk = bi;
            }
        }
    }
    if (tid < 128) {
        assignv[r0 + tid] = bbk;
        if (assign16) assign16[r0 + tid] = (unsigned short)bbk;
    }
}

// ---------------------------------------------------------------------------
// Fast M-step, phase 1: 2048 blocks = 4 per cluster. Deterministic.
// ---------------------------------------------------------------------------
__global__ __launch_bounds__(256) void update_partial_kernel(
    const float* __restrict__ E, const unsigned short* __restrict__ assign16,
    float* __restrict__ ws_sums, int* __restrict__ ws_cnts)
{
    const int b   = blockIdx.x;
    const int k   = b >> 2;
    const int qtr = b & 3;

    __shared__ float acc[4][DD];
    __shared__ int   cnts[4];

    const int tid  = threadIdx.x;
    const int w    = tid >> 6;
    const int lane = tid & 63;

    float a0 = 0.f, a1 = 0.f;
    int cnt = 0;
    const int wbase = qtr * (NN / 4) + w * (NN / 16);

    for (int it = 0; it < (NN / 16) / 512; ++it) {
        const int off = wbase + it * 512;
        uint4 p = *(const uint4*)&assign16[off + lane * 8];
        unsigned v[4] = {p.x, p.y, p.z, p.w};
#pragma unroll
        for (int h = 0; h < 4; ++h) {
            int lo = (int)(v[h] & 0xffffu);
            int hi = (int)(v[h] >> 16);
            unsigned long long mlo = __ballot(lo == k);
            unsigned long long mhi = __ballot(hi == k);
            cnt += (int)__popcll(mlo) + (int)__popcll(mhi);
            while (mlo) {
                int b2 = __ffsll((long long)mlo) - 1; mlo &= mlo - 1;
                int row = off + b2 * 8 + h * 2;
                float2 e = *(const float2*)&E[(size_t)row * DD + lane * 2];
                a0 += e.x; a1 += e.y;
            }
            while (mhi) {
                int b2 = __ffsll((long long)mhi) - 1; mhi &= mhi - 1;
                int row = off + b2 * 8 + h * 2 + 1;
                float2 e = *(const float2*)&E[(size_t)row * DD + lane * 2];
                a0 += e.x; a1 += e.y;
            }
        }
    }
    acc[w][lane * 2]     = a0;
    acc[w][lane * 2 + 1] = a1;
    if (lane == 0) cnts[w] = cnt;
    __syncthreads();
    if (tid < DD)
        ws_sums[(size_t)b * DD + tid] = acc[0][tid] + acc[1][tid] + acc[2][tid] + acc[3][tid];
    if (tid == 0)
        ws_cnts[b] = cnts[0] + cnts[1] + cnts[2] + cnts[3];
}

// ---------------------------------------------------------------------------
// Fast M-step, phase 2: combine 4 partials, mean, L2-normalize.
// ---------------------------------------------------------------------------
__global__ __launch_bounds__(128) void update_combine_kernel(
    const float* __restrict__ ws_sums, const int* __restrict__ ws_cnts,
    float* __restrict__ C)
{
    const int k = blockIdx.x, t = threadIdx.x;
    __shared__ float red[2];
    const int w = t >> 6, lane = t & 63;

    float s = ws_sums[(size_t)(4 * k + 0) * DD + t]
            + ws_sums[(size_t)(4 * k + 1) * DD + t]
            + ws_sums[(size_t)(4 * k + 2) * DD + t]
            + ws_sums[(size_t)(4 * k + 3) * DD + t];
    int cnt = ws_cnts[4 * k] + ws_cnts[4 * k + 1] + ws_cnts[4 * k + 2] + ws_cnts[4 * k + 3];
    float m = (cnt > 0) ? s / (float)cnt : C[k * DD + t];

    float sq = m * m;
#pragma unroll
    for (int o = 32; o > 0; o >>= 1) sq += __shfl_down(sq, o, 64);
    if (lane == 0) red[w] = sq;
    __syncthreads();
    float nrm = fmaxf(sqrtf(red[0] + red[1]), 1e-12f);
    C[k * DD + t] = m / nrm;
}

// ---------------------------------------------------------------------------
// Fallback M-step (no d_ws usage).
// ---------------------------------------------------------------------------
__global__ __launch_bounds__(256) void update_kernel(
    const float* __restrict__ E, const int* __restrict__ assignv,
    float* __restrict__ C)
{
    const int k = blockIdx.x;
    __shared__ float acc[4][DD];
    __shared__ int   cnts[4];
    __shared__ float red[4];

    const int tid  = threadIdx.x;
    const int w    = tid >> 6;
    const int lane = tid & 63;

    float a0 = 0.f, a1 = 0.f;
    int cnt = 0;
    const int per_wave = NN / 4;
    const int base = w * per_wave;

    for (int it = 0; it < per_wave / 256; ++it) {
        const int off = base + it * 256;
        int4 as = *(const int4*)&assignv[off + lane * 4];
        int av[4] = {as.x, as.y, as.z, as.w};
#pragma unroll
        for (int ci = 0; ci < 4; ++ci) {
            unsigned long long m = __ballot(av[ci] == k);
            cnt += (int)__popcll(m);
            while (m) {
                int b = __ffsll((long long)m) - 1;
                m &= m - 1;
                int r = off + b * 4 + ci;
                float2 v = *(const float2*)&E[r * DD + lane * 2];
                a0 += v.x; a1 += v.y;
            }
        }
    }
    acc[w][lane * 2]     = a0;
    acc[w][lane * 2 + 1] = a1;
    if (lane == 0) cnts[w] = cnt;
    __syncthreads();

    float m = 0.f;
    const int ctot = cnts[0] + cnts[1] + cnts[2] + cnts[3];
    if (tid < DD) {
        float s = acc[0][tid] + acc[1][tid] + acc[2][tid] + acc[3][tid];
        m = (ctot > 0) ? s / (float)ctot : C[k * DD + tid];
    }
    float sq = m * m;
#pragma unroll
    for (int o = 32; o > 0; o >>= 1) sq += __shfl_down(sq, o, 64);
    if (lane == 0) red[w] = sq;
    __syncthreads();
    if (tid < DD) {
        float nrm = fmaxf(sqrtf(red[0] + red[1]), 1e-12f);
        C[k * DD + tid] = m / nrm;
    }
}

__global__ void finalize_kernel(float* __restrict__ out)
{
    int i = blockIdx.x * 256 + threadIdx.x;
    if (i < NN) {
        int a = ((const int*)out)[i];
        out[i] = (float)a;
    }
}

extern "C" void kernel_launch(void* const* d_in, const int* in_sizes, int n_in,
                              void* d_out, int out_size, void* d_ws, size_t ws_size,
                              hipStream_t stream)
{
    (void)in_sizes; (void)n_in; (void)out_size;

    const float* E  = (const float*)d_in[0];
    const float* C0 = (const float*)d_in[1];
    // num_iters (d_in[2]) is a fixed scalar = 5; hardcoded (graph-safe).

    float* out     = (float*)d_out;
    float* C       = out + NN;        // centroids in d_out tail
    int*   assignv = (int*)out;       // assign ints in d_out head

    const bool fast = (ws_size >= (size_t)WS_NEEDED);
    unsigned short* assign16 = fast ? (unsigned short*)d_ws : nullptr;
    float* ws_sums = fast ? (float*)((char*)d_ws + WS_SUMS_OFF) : nullptr;
    int*   ws_cnts = fast ? (int*)((char*)d_ws + WS_CNTS_OFF) : nullptr;
    unsigned char* flags = fast ? (unsigned char*)d_ws + WS_SUMS_OFF : nullptr;
    unsigned short* CH = fast ? (unsigned short*)((char*)d_ws + WS_CH_OFF) : nullptr;
    unsigned short* CL = fast ? (unsigned short*)((char*)d_ws + WS_CL_OFF) : nullptr;

    hipMemcpyAsync(C, C0, (size_t)KK * DD * sizeof(float),
                   hipMemcpyDeviceToDevice, stream);

    for (int it = 0; it < NITER; ++it) {
        if (fast) {
            split_c_kernel<<<KK * DD / 4 / 256, 256, 0, stream>>>(C, CH, CL);
            assign_kernel<<<NN / 128, 256, 0, stream>>>(E, CH, CL, assignv, assign16, flags);
            rescue_kernel<<<NN / 128, 256, 0, stream>>>(E, C, flags, assignv, assign16);
            update_partial_kernel<<<2048, 256, 0, stream>>>(E, assign16, ws_sums, ws_cnts);
            update_combine_kernel<<<KK, 128, 0, stream>>>(ws_sums, ws_cnts, C);
        } else {
            assign_valu_kernel<<<NN / 128, 256, 0, stream>>>(E, C, assignv, nullptr);
            update_kernel<<<KK, 256, 0, stream>>>(E, assignv, C);
        }
    }
    finalize_kernel<<<(NN + 255) / 256, 256, 0, stream>>>(out);
}